// Round 7
// baseline (282.084 us; speedup 1.0000x reference)
//
#include <hip/hip_runtime.h>

// Problem constants (B=32, N=256, D=256 -> M=8192)
#define M_ROWS 8192
#define D_DIM  256
#define BM     128                // block tile rows (4 waves x 32)
#define BN     64                 // cols per step
#define NBI    (M_ROWS / BM)      // 64 i-tiles
#define NJQ    (M_ROWS / 256)     // 32 j-quads (4 steps x 64 cols each)
#define NJOBS  (NBI * NJQ)        // 2048 gemm blocks

// Fold 1/TEMP * log2(e) into normalization: acc = log2(e)*sim/TEMP, e = exp2(acc)
#define ALPHA  4.53982478f        // sqrt(log2(e)/0.07)

// fp8 fragment layout for mfma_scale_f32_16x16x128_f8f6f4 (K=128 per MFMA):
//   tile16 = 16 rows x 256 k = 4 KB, at tile*4096
//   per k-step s (0/1, K=128 each): 2 KB chunk at +s*2048
//   within chunk: half h (0/1) at +h*1024, then lane*16 bytes
//   lane l holds row (l&15), k = s*128 + (l>>4)*32 + h*16 + byte(0..15)
// => every load/store/ds op is 64 lanes x 16 B fully contiguous (stride-16).

typedef __attribute__((ext_vector_type(4))) float floatx4;  // MFMA C/D
typedef __attribute__((ext_vector_type(2))) float floatx2;  // packed f32 pair
typedef __attribute__((ext_vector_type(8))) int   intx8;    // MFMA A/B (32 B fp8)

// async global->LDS, 16 B per lane; LDS dest = wave-uniform base + lane*16,
// which our (... + tid*16) addressing satisfies exactly.
#define GLOAD_LDS16(gp, lp) \
    __builtin_amdgcn_global_load_lds( \
        (__attribute__((address_space(1))) void*)(gp), \
        (__attribute__((address_space(3))) void*)(lp), 16, 0, 0)

__device__ inline float fast_exp2(float x) {
#if __has_builtin(__builtin_amdgcn_exp2f)
    return __builtin_amdgcn_exp2f(x);
#else
    return exp2f(x);
#endif
}

// MX-scaled fp8 MFMA with unit scales (E8M0 bias 127 -> 2^0). cbsz/blgp = 0 = OCP e4m3.
__device__ inline floatx4 mfma_fp8(intx8 a, intx8 b, floatx4 c) {
    return __builtin_amdgcn_mfma_scale_f32_16x16x128_f8f6f4(
        a, b, c, 0, 0, 0, 0x7f7f7f7f, 0, 0x7f7f7f7f);
}

// Kernel 1: L2-normalize, scale by ALPHA, emit fp8 e4m3 in fragment order.
// Each thread loads exactly the 16 f32 it emits (64 B contiguous); only the
// row-norm is cross-thread (2 shuffles + tiny LDS). Output store = dst + t*16,
// fully coalesced. Block 0 zeroes the finalize accumulators.
__global__ __launch_bounds__(256) void normalize_kernel(
    const float* __restrict__ af, const float* __restrict__ vf,
    unsigned char* __restrict__ aB, unsigned char* __restrict__ vB,
    float* __restrict__ glob)
{
    __shared__ float ssb[16][4];

    if (blockIdx.x == 0) {
        if (threadIdx.x < 4) glob[threadIdx.x] = 0.f;
        if (threadIdx.x == 4) ((int*)glob)[4] = 0;
    }

    const int b = blockIdx.x;            // 0..1023
    const bool isA = b < 512;
    const int T = isA ? b : b - 512;     // tile16 index 0..511
    const float* src = (isA ? af : vf) + (size_t)T * 16 * D_DIM;
    unsigned char* dst = (isA ? aB : vB) + (size_t)T * 4096;

    const int t    = threadIdx.x;
    const int wave = t >> 6, lane = t & 63;
    const int row  = t & 15;             // == lane & 15
    const int kq   = (t >> 4) & 3;
    const int h    = (t >> 6) & 1;
    const int s    = t >> 7;
    const int kbase = s * 128 + kq * 32 + h * 16;

    const float* p = src + row * D_DIM + kbase;
    float4 x0 = ((const float4*)p)[0], x1 = ((const float4*)p)[1];
    float4 x2 = ((const float4*)p)[2], x3 = ((const float4*)p)[3];

    float ss = x0.x*x0.x + x0.y*x0.y + x0.z*x0.z + x0.w*x0.w
             + x1.x*x1.x + x1.y*x1.y + x1.z*x1.z + x1.w*x1.w
             + x2.x*x2.x + x2.y*x2.y + x2.z*x2.z + x2.w*x2.w
             + x3.x*x3.x + x3.y*x3.y + x3.z*x3.z + x3.w*x3.w;
    // within a wave, lanes differing in bits 4..5 are the 4 kq groups of this row
    ss += __shfl_xor(ss, 16, 64);
    ss += __shfl_xor(ss, 32, 64);
    if (lane < 16) ssb[lane][wave] = ss;
    __syncthreads();
    float tot = ssb[row][0] + ssb[row][1] + ssb[row][2] + ssb[row][3];
    float scale = ALPHA / fmaxf(sqrtf(tot), 1e-12f);

    int4 o;
    int pk;
    pk  = __builtin_amdgcn_cvt_pk_fp8_f32(x0.x*scale, x0.y*scale, 0, false);
    pk  = __builtin_amdgcn_cvt_pk_fp8_f32(x0.z*scale, x0.w*scale, pk, true);
    o.x = pk;
    pk  = __builtin_amdgcn_cvt_pk_fp8_f32(x1.x*scale, x1.y*scale, 0, false);
    pk  = __builtin_amdgcn_cvt_pk_fp8_f32(x1.z*scale, x1.w*scale, pk, true);
    o.y = pk;
    pk  = __builtin_amdgcn_cvt_pk_fp8_f32(x2.x*scale, x2.y*scale, 0, false);
    pk  = __builtin_amdgcn_cvt_pk_fp8_f32(x2.z*scale, x2.w*scale, pk, true);
    o.z = pk;
    pk  = __builtin_amdgcn_cvt_pk_fp8_f32(x3.x*scale, x3.y*scale, 0, false);
    pk  = __builtin_amdgcn_cvt_pk_fp8_f32(x3.z*scale, x3.w*scale, pk, true);
    o.w = pk;
    *(int4*)(dst + (size_t)t * 16) = o;
}

// One j-step: optional async-stage of tile T+1 into LDSWR, then 16 MFMAs +
// epilogue on tile T from LDSRD. acc lives 8 regs at a time (per-jt). All
// register arrays statically indexed; buffers are NAMED (no parity index).
#define GEMM_STEP(T, LDSRD, LDSWR, DOSTAGE)                                    \
    {                                                                          \
        if (DOSTAGE) {                                                         \
            const unsigned char* vsrc_ = vB + (size_t)(jq * 4 + (T) + 1) * 16384 \
                                            + (size_t)tid * 16;                \
            unsigned char* ld_ = (LDSWR) + tid * 16;                           \
            GLOAD_LDS16(vsrc_,         ld_);                                   \
            GLOAD_LDS16(vsrc_ +  4096, ld_ +  4096);                           \
            GLOAD_LDS16(vsrc_ +  8192, ld_ +  8192);                           \
            GLOAD_LDS16(vsrc_ + 12288, ld_ + 12288);                           \
        }                                                                      \
        const unsigned char* Bl_ = (LDSRD) + lane * 16;                        \
        _Pragma("unroll")                                                      \
        for (int jt = 0; jt < 4; ++jt) {                                       \
            int4 h0a = *(const int4*)(Bl_ + jt * 4096);                        \
            int4 h1a = *(const int4*)(Bl_ + jt * 4096 + 1024);                 \
            int4 h0b = *(const int4*)(Bl_ + jt * 4096 + 2048);                 \
            int4 h1b = *(const int4*)(Bl_ + jt * 4096 + 3072);                 \
            intx8 bf0 = intx8{h0a.x,h0a.y,h0a.z,h0a.w,h1a.x,h1a.y,h1a.z,h1a.w};\
            intx8 bf1 = intx8{h0b.x,h0b.y,h0b.z,h0b.w,h1b.x,h1b.y,h1b.z,h1b.w};\
            floatx4 a0 = {}, a1 = {};                                          \
            a0 = mfma_fp8(afr[0][0], bf0, a0);                                 \
            a0 = mfma_fp8(afr[0][1], bf1, a0);                                 \
            a1 = mfma_fp8(afr[1][0], bf0, a1);                                 \
            a1 = mfma_fp8(afr[1][1], bf1, a1);                                 \
            floatx2 mj_ = floatx2{1.f,                                         \
                (float)lv[j0 + (T) * 64 + jt * 16 + l16]};                     \
            floatx2 ca_ = {};                                                  \
            _Pragma("unroll")                                                  \
            for (int r = 0; r < 4; ++r) {                                      \
                float e0 = fast_exp2(a0[r]);                                   \
                floatx2 e02 = {e0, e0};                                        \
                rowacc[0][r] = e02 * mj_ + rowacc[0][r];                       \
                ca_ = e02 * ma2[0][r] + ca_;                                   \
                float e1 = fast_exp2(a1[r]);                                   \
                floatx2 e12 = {e1, e1};                                        \
                rowacc[1][r] = e12 * mj_ + rowacc[1][r];                       \
                ca_ = e12 * ma2[1][r] + ca_;                                   \
            }                                                                  \
            ca_.x += __shfl_xor(ca_.x, 16, 64);                                \
            ca_.y += __shfl_xor(ca_.y, 16, 64);                                \
            ca_.x += __shfl_xor(ca_.x, 32, 64);                                \
            ca_.y += __shfl_xor(ca_.y, 32, 64);                                \
            if (quad == 0) colbuf[(T)][wave][jt * 16 + l16] = ca_;             \
        }                                                                      \
    }

// Kernel 2: fused GEMM (acc = log2e*sim/T) via MX-scaled fp8 K=128 MFMA,
// exp2 + packed (total,class1) sums. Block = 128 rows x 256 cols as 4
// explicitly-expanded 64-col steps with named double-buffer LDS prefetch
// (stage T+1 hides under compute T; 1 barrier per step). A fragments, row
// labels, rowacc amortized over all 4 steps. VGPR cap 168 (no spill),
// LDS 41 KB -> 3 blocks/CU.
__global__ __launch_bounds__(256, 3) void gemm_loss_kernel(
    const unsigned char* __restrict__ aB, const unsigned char* __restrict__ vB,
    const int* __restrict__ la, const int* __restrict__ lv,
    float* __restrict__ rowPart, float* __restrict__ colPart)
{
    __shared__ __align__(16) unsigned char ldsB0[16384];  // later rp[128][16] float2
    __shared__ __align__(16) unsigned char ldsB1[16384];
    __shared__ floatx2 colbuf[4][4][64];                  // [step][wave][col] = 8 KB

    const int tid  = threadIdx.x;
    const int wave = tid >> 6, lane = tid & 63;
    const int quad = lane >> 4, l16 = lane & 15;

    // 64 consecutive blocks share one 256-col B range (64 KB, L2-hot)
    const int bx = blockIdx.x & 63;             // i-tile (128 rows)
    const int jq = blockIdx.x >> 6;             // j-quad (256 cols)
    const int i0 = bx * BM, j0 = jq * 256;

    // ---- prologue: stage tile 0 into ldsB0 (async, no VGPR round-trip)
    {
        const unsigned char* vsrc = vB + (size_t)(jq * 4) * 16384 + (size_t)tid * 16;
        unsigned char* ld = ldsB0 + tid * 16;
        GLOAD_LDS16(vsrc,         ld);
        GLOAD_LDS16(vsrc +  4096, ld +  4096);
        GLOAD_LDS16(vsrc +  8192, ld +  8192);
        GLOAD_LDS16(vsrc + 12288, ld + 12288);
    }

    // ---- A fragments [it][s]: 32 B each, halves at +0 / +1024 (once per block)
    const unsigned char* Abase = aB + (size_t)(bx * 8 + wave * 2) * 4096
                                    + (size_t)lane * 16;
    intx8 afr[2][2];
    #pragma unroll
    for (int it = 0; it < 2; ++it) {
        #pragma unroll
        for (int s = 0; s < 2; ++s) {
            int4 h0 = *(const int4*)(Abase + it * 4096 + s * 2048);
            int4 h1 = *(const int4*)(Abase + it * 4096 + s * 2048 + 1024);
            afr[it][s] = intx8{h0.x, h0.y, h0.z, h0.w, h1.x, h1.y, h1.z, h1.w};
        }
    }

    // ---- row labels as packed (1, label), once per block
    const int baseRow = i0 + wave * 32;
    floatx2 ma2[2][4];
    #pragma unroll
    for (int it = 0; it < 2; ++it)
        #pragma unroll
        for (int r = 0; r < 4; ++r)
            ma2[it][r] = floatx2{1.f, (float)la[baseRow + it * 16 + quad * 4 + r]};

    floatx2 rowacc[2][4] = {};      // (tot, c1) accumulated over all 4 steps

    __syncthreads();                // tile 0 landed (vmcnt drained)

    GEMM_STEP(0, ldsB0, ldsB1, 1)
    __syncthreads();                // tile 1 landed; step-0 reads done
    GEMM_STEP(1, ldsB1, ldsB0, 1)
    __syncthreads();
    GEMM_STEP(2, ldsB0, ldsB1, 1)
    __syncthreads();
    GEMM_STEP(3, ldsB1, ldsB0, 0)
    __syncthreads();                // all B reads done -> alias ldsB0 as rp

    // ---- row partials -> LDS transpose buffer rp[row 0..127][slot = l16]
    floatx2* rp = (floatx2*)ldsB0;
    #pragma unroll
    for (int it = 0; it < 2; ++it)
        #pragma unroll
        for (int r = 0; r < 4; ++r)
            rp[(wave * 32 + it * 16 + quad * 4 + r) * 16 + l16] = rowacc[it][r];
    __syncthreads();

    // ---- final sums + coalesced global writes
    {
        const int row = tid >> 1, h = tid & 1;      // 2 threads per row
        const float4* b4 = (const float4*)(rp + (size_t)row * 16 + h * 8);
        float4 q0 = b4[0], q1 = b4[1], q2 = b4[2], q3 = b4[3];
        floatx2 s = floatx2{q0.x, q0.y} + floatx2{q0.z, q0.w}
                  + floatx2{q1.x, q1.y} + floatx2{q1.z, q1.w}
                  + floatx2{q2.x, q2.y} + floatx2{q2.z, q2.w}
                  + floatx2{q3.x, q3.y} + floatx2{q3.z, q3.w};
        s.x += __shfl_xor(s.x, 1, 64);
        s.y += __shfl_xor(s.y, 1, 64);
        if (h == 0)
            *(floatx2*)&rowPart[((size_t)jq * M_ROWS + i0 + row) * 2] = s;

        // cols: tid -> (step = tid>>6, col = tid&63); global col = j0 + tid
        const int st = tid >> 6, cl = tid & 63;
        floatx2 c = colbuf[st][0][cl] + colbuf[st][1][cl]
                  + colbuf[st][2][cl] + colbuf[st][3][cl];
        *(floatx2*)&colPart[((size_t)bx * M_ROWS + j0 + tid) * 2] = c;
    }
}

// Kernel 3: reduce partials (32 row-slabs / 64 col-slabs), per-row/col log
// terms, then merged finalize: per-block (sum,count) -> device atomicAdd; last
// block (atomic counter) computes the final scalar. Blocks 0..31 = rows,
// 32..63 = cols. glob: [sumA, cntA, sumV, cntV, (int)counter].
__global__ __launch_bounds__(256) void reduce_kernel(
    const float* __restrict__ rowPart, const float* __restrict__ colPart,
    const int* __restrict__ la, const int* __restrict__ lv,
    float* __restrict__ glob, float* __restrict__ out)
{
    const int bid = blockIdx.x;
    const bool aside = bid < 32;
    const int idx = (aside ? bid : bid - 32) * 256 + threadIdx.x;   // row or col index
    const float* part = aside ? rowPart : colPart;
    const int* lab = aside ? la : lv;
    const int nslab = aside ? NJQ : NBI;    // rows: 32 slabs, cols: 64 slabs

    float tot = 0.f, c1 = 0.f;
    #pragma unroll 4
    for (int b = 0; b < nslab; ++b) {
        float2 p = *(const float2*)(part + ((size_t)b * M_ROWS + idx) * 2);
        tot += p.x; c1 += p.y;
    }
    float num = lab[idx] ? c1 : 0.1f * (tot - c1);
    float lg = 0.f, cnt = 0.f;
    if (num > 0.f) { lg = logf((num + 1e-8f) / (tot + 1e-8f)); cnt = 1.f; }

    #pragma unroll
    for (int m = 1; m < 64; m <<= 1) {
        lg  += __shfl_xor(lg,  m, 64);
        cnt += __shfl_xor(cnt, m, 64);
    }
    __shared__ float red[4][2];
    const int w = threadIdx.x >> 6, ln = threadIdx.x & 63;
    if (ln == 0) { red[w][0] = lg; red[w][1] = cnt; }
    __syncthreads();
    if (threadIdx.x == 0) {
        float slg  = red[0][0] + red[1][0] + red[2][0] + red[3][0];
        float scnt = red[0][1] + red[1][1] + red[2][1] + red[3][1];
        float* base = glob + (aside ? 0 : 2);
        atomicAdd(&base[0], slg);
        atomicAdd(&base[1], scnt);
        __threadfence();
        int old = atomicAdd((int*)glob + 4, 1);
        if (old == 63) {
            __threadfence();
            float sA = atomicAdd(&glob[0], 0.f);
            float cA = atomicAdd(&glob[1], 0.f);
            float sV = atomicAdd(&glob[2], 0.f);
            float cV = atomicAdd(&glob[3], 0.f);
            float lossA = -sA / fmaxf(cA, 1.f);
            float lossV = -sV / fmaxf(cV, 1.f);
            out[0] = 0.5f * (lossA + lossV);
        }
    }
}

extern "C" void kernel_launch(void* const* d_in, const int* in_sizes, int n_in,
                              void* d_out, int out_size, void* d_ws, size_t ws_size,
                              hipStream_t stream)
{
    const float* af = (const float*)d_in[0];
    const float* vf = (const float*)d_in[1];
    const int*   la = (const int*)d_in[2];
    const int*   lv = (const int*)d_in[3];
    float* out = (float*)d_out;

    char* ws = (char*)d_ws;
    unsigned char* aB = (unsigned char*)ws;                            // 2 MiB (fp8 fragment order)
    unsigned char* vB = (unsigned char*)(ws + 2ull * 1024 * 1024);     // 2 MiB
    float* rowPart   = (float*)(ws +  4ull * 1024 * 1024);             // 2 MiB [32][8192][2]
    float* colPart   = (float*)(ws +  8ull * 1024 * 1024);             // 4 MiB [64][8192][2]
    float* glob      = (float*)(ws + 12ull * 1024 * 1024);             // 4 floats + counter

    normalize_kernel<<<1024, 256, 0, stream>>>(af, vf, aB, vB, glob);
    gemm_loss_kernel<<<NJOBS, 256, 0, stream>>>(aB, vB, la, lv, rowPart, colPart);
    reduce_kernel<<<64, 256, 0, stream>>>(rowPart, colPart, la, lv, glob, out);
}

// Round 8
// 192.612 us; speedup vs baseline: 1.4645x; 1.4645x over previous
//
#include <hip/hip_runtime.h>

// Problem constants (B=32, N=256, D=256 -> M=8192)
#define M_ROWS 8192
#define D_DIM  256
#define BM     128                // block tile rows (4 waves x 32)
#define BN     64                 // cols per tile; 2 tiles per block = 128 cols
#define NBI    (M_ROWS / BM)      // 64 i-tiles
#define NJP    (M_ROWS / 128)     // 64 j-pairs
#define NJOBS  (NBI * NJP)        // 4096 gemm blocks

// Fold 1/TEMP * log2(e) into normalization: acc = log2(e)*sim/TEMP, e = exp2(acc)
#define ALPHA  4.53982478f        // sqrt(log2(e)/0.07)

// fp8 fragment layout for mfma_scale_f32_16x16x128_f8f6f4 (K=128 per MFMA):
//   tile16 = 16 rows x 256 k = 4 KB, at tile*4096
//   per k-step s (0/1, K=128 each): 2 KB chunk at +s*2048
//   within chunk: half h (0/1) at +h*1024, then lane*16 bytes
//   lane l holds row (l&15), k = s*128 + (l>>4)*32 + h*16 + byte(0..15)
// => every load/store/ds op is 64 lanes x 16 B fully contiguous (stride-16).

typedef __attribute__((ext_vector_type(4))) float floatx4;  // MFMA C/D
typedef __attribute__((ext_vector_type(2))) float floatx2;  // packed f32 pair
typedef __attribute__((ext_vector_type(8))) int   intx8;    // MFMA A/B (32 B fp8)

// async global->LDS, 16 B per lane; LDS dest = wave-uniform base + lane*16,
// which our (... + tid*16) addressing satisfies exactly. ONLY used in the
// prologue, fully drained by the first barrier (the R4/R7 stage-during-
// compute pattern scratch-bombs this kernel shape -- never reintroduce).
#define GLOAD_LDS16(gp, lp) \
    __builtin_amdgcn_global_load_lds( \
        (__attribute__((address_space(1))) void*)(gp), \
        (__attribute__((address_space(3))) void*)(lp), 16, 0, 0)

__device__ inline float fast_exp2(float x) {
#if __has_builtin(__builtin_amdgcn_exp2f)
    return __builtin_amdgcn_exp2f(x);
#else
    return exp2f(x);
#endif
}

// MX-scaled fp8 MFMA with unit scales (E8M0 bias 127 -> 2^0). cbsz/blgp = 0 = OCP e4m3.
__device__ inline floatx4 mfma_fp8(intx8 a, intx8 b, floatx4 c) {
    return __builtin_amdgcn_mfma_scale_f32_16x16x128_f8f6f4(
        a, b, c, 0, 0, 0, 0x7f7f7f7f, 0, 0x7f7f7f7f);
}

// Kernel 1: L2-normalize, scale by ALPHA, emit fp8 e4m3 in fragment order.
// Each thread loads exactly the 16 f32 it emits (64 B contiguous); only the
// row-norm is cross-thread (2 shuffles + tiny LDS). Output store = dst + t*16,
// fully coalesced. Block 0 zeroes the finalize accumulators.
__global__ __launch_bounds__(256) void normalize_kernel(
    const float* __restrict__ af, const float* __restrict__ vf,
    unsigned char* __restrict__ aB, unsigned char* __restrict__ vB,
    float* __restrict__ glob)
{
    __shared__ float ssb[16][4];

    if (blockIdx.x == 0) {
        if (threadIdx.x < 4) glob[threadIdx.x] = 0.f;
        if (threadIdx.x == 4) ((int*)glob)[4] = 0;
    }

    const int b = blockIdx.x;            // 0..1023
    const bool isA = b < 512;
    const int T = isA ? b : b - 512;     // tile16 index 0..511
    const float* src = (isA ? af : vf) + (size_t)T * 16 * D_DIM;
    unsigned char* dst = (isA ? aB : vB) + (size_t)T * 4096;

    const int t    = threadIdx.x;
    const int wave = t >> 6, lane = t & 63;
    const int row  = t & 15;             // == lane & 15
    const int kq   = (t >> 4) & 3;
    const int h    = (t >> 6) & 1;
    const int s    = t >> 7;
    const int kbase = s * 128 + kq * 32 + h * 16;

    const float* p = src + row * D_DIM + kbase;
    float4 x0 = ((const float4*)p)[0], x1 = ((const float4*)p)[1];
    float4 x2 = ((const float4*)p)[2], x3 = ((const float4*)p)[3];

    float ss = x0.x*x0.x + x0.y*x0.y + x0.z*x0.z + x0.w*x0.w
             + x1.x*x1.x + x1.y*x1.y + x1.z*x1.z + x1.w*x1.w
             + x2.x*x2.x + x2.y*x2.y + x2.z*x2.z + x2.w*x2.w
             + x3.x*x3.x + x3.y*x3.y + x3.z*x3.z + x3.w*x3.w;
    // within a wave, lanes differing in bits 4..5 are the 4 kq groups of this row
    ss += __shfl_xor(ss, 16, 64);
    ss += __shfl_xor(ss, 32, 64);
    if (lane < 16) ssb[lane][wave] = ss;
    __syncthreads();
    float tot = ssb[row][0] + ssb[row][1] + ssb[row][2] + ssb[row][3];
    float scale = ALPHA / fmaxf(sqrtf(tot), 1e-12f);

    int4 o;
    int pk;
    pk  = __builtin_amdgcn_cvt_pk_fp8_f32(x0.x*scale, x0.y*scale, 0, false);
    pk  = __builtin_amdgcn_cvt_pk_fp8_f32(x0.z*scale, x0.w*scale, pk, true);
    o.x = pk;
    pk  = __builtin_amdgcn_cvt_pk_fp8_f32(x1.x*scale, x1.y*scale, 0, false);
    pk  = __builtin_amdgcn_cvt_pk_fp8_f32(x1.z*scale, x1.w*scale, pk, true);
    o.y = pk;
    pk  = __builtin_amdgcn_cvt_pk_fp8_f32(x2.x*scale, x2.y*scale, 0, false);
    pk  = __builtin_amdgcn_cvt_pk_fp8_f32(x2.z*scale, x2.w*scale, pk, true);
    o.z = pk;
    pk  = __builtin_amdgcn_cvt_pk_fp8_f32(x3.x*scale, x3.y*scale, 0, false);
    pk  = __builtin_amdgcn_cvt_pk_fp8_f32(x3.z*scale, x3.w*scale, pk, true);
    o.w = pk;
    *(int4*)(dst + (size_t)t * 16) = o;
}

// Kernel 2: fused GEMM (acc = log2e*sim/T) via MX-scaled fp8 K=128 MFMA,
// exp2 + packed (total,class1) sums. R6's proven flat 2-barrier skeleton,
// widened: BOTH 64-col B tiles (32 KB) staged in ONE prologue async batch,
// then tile 0 and tile 1 computed back-to-back with no extra barriers.
// A frags / labels / rowacc / row-reduce amortized over 16K outputs.
// LDS 36.6 KB, VGPR ~90 under (256,4) cap 128 -> no scratch.
__global__ __launch_bounds__(256, 4) void gemm_loss_kernel(
    const unsigned char* __restrict__ aB, const unsigned char* __restrict__ vB,
    const int* __restrict__ la, const int* __restrict__ lv,
    float* __restrict__ rowPart, float* __restrict__ colPart)
{
    __shared__ __align__(16) unsigned char ldsB[32768]; // 2 B tiles; later rp[128][16] float2
    __shared__ floatx2 colbuf[2][4][BN];                // [tile][wave][col] = 4 KB

    const int tid  = threadIdx.x;
    const int wave = tid >> 6, lane = tid & 63;
    const int quad = lane >> 4, l16 = lane & 15;

    // 64 consecutive blocks share one 128-col B pair (32 KB, L2-hot)
    const int bx = blockIdx.x & 63;             // i-tile (128 rows)
    const int jp = blockIdx.x >> 6;             // j-pair (128 cols)
    const int i0 = bx * BM, j0 = jp * 128;

    // ---- prologue: stage BOTH B tiles (async), drained by the one barrier
    {
        const unsigned char* vsrc = vB + (size_t)jp * 32768 + (size_t)tid * 16;
        unsigned char* ld = ldsB + tid * 16;
        #pragma unroll
        for (int c = 0; c < 8; ++c)
            GLOAD_LDS16(vsrc + c * 4096, ld + c * 4096);
    }

    // ---- A fragments [it][s]: 32 B each, halves at +0 / +1024 (once per block)
    const unsigned char* Abase = aB + (size_t)(bx * 8 + wave * 2) * 4096
                                    + (size_t)lane * 16;
    intx8 afr[2][2];
    #pragma unroll
    for (int it = 0; it < 2; ++it) {
        #pragma unroll
        for (int s = 0; s < 2; ++s) {
            int4 h0 = *(const int4*)(Abase + it * 4096 + s * 2048);
            int4 h1 = *(const int4*)(Abase + it * 4096 + s * 2048 + 1024);
            afr[it][s] = intx8{h0.x, h0.y, h0.z, h0.w, h1.x, h1.y, h1.z, h1.w};
        }
    }

    // ---- row labels as packed (1, label), once per block
    const int baseRow = i0 + wave * 32;
    floatx2 ma2[2][4];
    #pragma unroll
    for (int it = 0; it < 2; ++it)
        #pragma unroll
        for (int r = 0; r < 4; ++r)
            ma2[it][r] = floatx2{1.f, (float)la[baseRow + it * 16 + quad * 4 + r]};

    floatx2 rowacc[2][4] = {};      // (tot, c1) accumulated over both tiles

    __syncthreads();    // drains vmcnt (incl. all global_load_lds) -> B ready

    // ---- two tiles back-to-back, no barriers in between (both staged)
    #pragma unroll
    for (int T = 0; T < 2; ++T) {
        const unsigned char* Bl = ldsB + T * 16384 + lane * 16;

        floatx4 acc[2][4] = {};
        #pragma unroll
        for (int s = 0; s < 2; ++s) {
            #pragma unroll
            for (int jt = 0; jt < 4; ++jt) {
                int4 h0 = *(const int4*)(Bl + jt * 4096 + s * 2048);
                int4 h1 = *(const int4*)(Bl + jt * 4096 + s * 2048 + 1024);
                intx8 bf = intx8{h0.x, h0.y, h0.z, h0.w, h1.x, h1.y, h1.z, h1.w};
                acc[0][jt] = mfma_fp8(afr[0][s], bf, acc[0][jt]);
                acc[1][jt] = mfma_fp8(afr[1][s], bf, acc[1][jt]);
            }
        }

        // epilogue(T): exp2 + packed accumulate; C/D: col = l16, row = quad*4+r
        #pragma unroll
        for (int jt = 0; jt < 4; ++jt) {
            floatx2 mj = floatx2{1.f, (float)lv[j0 + T * 64 + jt * 16 + l16]};
            floatx2 ca = {};
            #pragma unroll
            for (int r = 0; r < 4; ++r) {
                float e0 = fast_exp2(acc[0][jt][r]);
                floatx2 e02 = {e0, e0};
                rowacc[0][r] = e02 * mj + rowacc[0][r];     // v_pk_fma_f32
                ca = e02 * ma2[0][r] + ca;
                float e1 = fast_exp2(acc[1][jt][r]);
                floatx2 e12 = {e1, e1};
                rowacc[1][r] = e12 * mj + rowacc[1][r];
                ca = e12 * ma2[1][r] + ca;
            }
            // col partial: reduce over quads within wave (register-only)
            ca.x += __shfl_xor(ca.x, 16, 64); ca.y += __shfl_xor(ca.y, 16, 64);
            ca.x += __shfl_xor(ca.x, 32, 64); ca.y += __shfl_xor(ca.y, 32, 64);
            if (quad == 0) colbuf[T][wave][jt * 16 + l16] = ca;
        }
    }

    __syncthreads();    // all waves done reading ldsB -> safe to alias as rp

    // ---- row partials -> LDS transpose buffer rp[row 0..127][slot = l16]
    floatx2* rp = (floatx2*)ldsB;
    #pragma unroll
    for (int it = 0; it < 2; ++it)
        #pragma unroll
        for (int r = 0; r < 4; ++r)
            rp[(wave * 32 + it * 16 + quad * 4 + r) * 16 + l16] = rowacc[it][r];
    __syncthreads();

    // ---- final sums + coalesced global writes
    {
        const int row = tid >> 1, h = tid & 1;      // 2 threads per row
        const float4* b4 = (const float4*)(rp + (size_t)row * 16 + h * 8);
        float4 q0 = b4[0], q1 = b4[1], q2 = b4[2], q3 = b4[3];
        floatx2 s = floatx2{q0.x, q0.y} + floatx2{q0.z, q0.w}
                  + floatx2{q1.x, q1.y} + floatx2{q1.z, q1.w}
                  + floatx2{q2.x, q2.y} + floatx2{q2.z, q2.w}
                  + floatx2{q3.x, q3.y} + floatx2{q3.z, q3.w};
        s.x += __shfl_xor(s.x, 1, 64);
        s.y += __shfl_xor(s.y, 1, 64);
        if (h == 0)
            *(floatx2*)&rowPart[((size_t)jp * M_ROWS + i0 + row) * 2] = s;

        // cols: 128 cols per block; threads 0..127 each sum the 4 waves
        if (tid < 128) {
            const int T = tid >> 6, cl = tid & 63;
            floatx2 c = colbuf[T][0][cl] + colbuf[T][1][cl]
                      + colbuf[T][2][cl] + colbuf[T][3][cl];
            *(floatx2*)&colPart[((size_t)bx * M_ROWS + j0 + tid) * 2] = c;
        }
    }
}

// Kernel 3: reduce partials (64 row-slabs / 64 col-slabs), per-row/col log
// terms, then merged finalize: per-block (sum,count) -> device atomicAdd; last
// block (atomic counter) computes the final scalar. Blocks 0..31 = rows,
// 32..63 = cols. glob: [sumA, cntA, sumV, cntV, (int)counter].
__global__ __launch_bounds__(256) void reduce_kernel(
    const float* __restrict__ rowPart, const float* __restrict__ colPart,
    const int* __restrict__ la, const int* __restrict__ lv,
    float* __restrict__ glob, float* __restrict__ out)
{
    const int bid = blockIdx.x;
    const bool aside = bid < 32;
    const int idx = (aside ? bid : bid - 32) * 256 + threadIdx.x;   // row or col index
    const float* part = aside ? rowPart : colPart;
    const int* lab = aside ? la : lv;
    const int nslab = aside ? NJP : NBI;    // rows: 64 slabs, cols: 64 slabs

    float tot = 0.f, c1 = 0.f;
    #pragma unroll 4
    for (int b = 0; b < nslab; ++b) {
        float2 p = *(const float2*)(part + ((size_t)b * M_ROWS + idx) * 2);
        tot += p.x; c1 += p.y;
    }
    float num = lab[idx] ? c1 : 0.1f * (tot - c1);
    float lg = 0.f, cnt = 0.f;
    if (num > 0.f) { lg = logf((num + 1e-8f) / (tot + 1e-8f)); cnt = 1.f; }

    #pragma unroll
    for (int m = 1; m < 64; m <<= 1) {
        lg  += __shfl_xor(lg,  m, 64);
        cnt += __shfl_xor(cnt, m, 64);
    }
    __shared__ float red[4][2];
    const int w = threadIdx.x >> 6, ln = threadIdx.x & 63;
    if (ln == 0) { red[w][0] = lg; red[w][1] = cnt; }
    __syncthreads();
    if (threadIdx.x == 0) {
        float slg  = red[0][0] + red[1][0] + red[2][0] + red[3][0];
        float scnt = red[0][1] + red[1][1] + red[2][1] + red[3][1];
        float* base = glob + (aside ? 0 : 2);
        atomicAdd(&base[0], slg);
        atomicAdd(&base[1], scnt);
        __threadfence();
        int old = atomicAdd((int*)glob + 4, 1);
        if (old == 63) {
            __threadfence();
            float sA = atomicAdd(&glob[0], 0.f);
            float cA = atomicAdd(&glob[1], 0.f);
            float sV = atomicAdd(&glob[2], 0.f);
            float cV = atomicAdd(&glob[3], 0.f);
            float lossA = -sA / fmaxf(cA, 1.f);
            float lossV = -sV / fmaxf(cV, 1.f);
            out[0] = 0.5f * (lossA + lossV);
        }
    }
}

extern "C" void kernel_launch(void* const* d_in, const int* in_sizes, int n_in,
                              void* d_out, int out_size, void* d_ws, size_t ws_size,
                              hipStream_t stream)
{
    const float* af = (const float*)d_in[0];
    const float* vf = (const float*)d_in[1];
    const int*   la = (const int*)d_in[2];
    const int*   lv = (const int*)d_in[3];
    float* out = (float*)d_out;

    char* ws = (char*)d_ws;
    unsigned char* aB = (unsigned char*)ws;                            // 2 MiB (fp8 fragment order)
    unsigned char* vB = (unsigned char*)(ws + 2ull * 1024 * 1024);     // 2 MiB
    float* rowPart   = (float*)(ws +  4ull * 1024 * 1024);             // 4 MiB [64][8192][2]
    float* colPart   = (float*)(ws +  8ull * 1024 * 1024);             // 4 MiB [64][8192][2]
    float* glob      = (float*)(ws + 12ull * 1024 * 1024);             // 4 floats + counter

    normalize_kernel<<<1024, 256, 0, stream>>>(af, vf, aB, vB, glob);
    gemm_loss_kernel<<<NJOBS, 256, 0, stream>>>(aB, vB, la, lv, rowPart, colPart);
    reduce_kernel<<<64, 256, 0, stream>>>(rowPart, colPart, la, lv, glob, out);
}